// Round 9
// baseline (978.154 us; speedup 1.0000x reference)
//
#include <hip/hip_runtime.h>
#include <stdint.h>

#define N_NODES   50000
#define N_EDGES   800000
#define IN_DIM    128
#define OUT_DIM   128
#define NUM_RELS  8
#define THREADS   256

typedef _Float16 half_t;
typedef _Float16 half2v __attribute__((ext_vector_type(2)));
typedef _Float16 half8 __attribute__((ext_vector_type(8)));
typedef float floatx4 __attribute__((ext_vector_type(4)));

// ============ plan (round 9): CSR front-end + agg + K-SPLIT gemm3 ============
// Round-8 lesson: wave-tile gemm2 was GRID-starved (3128 waves = 3.05/SIMD);
// compiler serialized frag loads (VGPR 76) exposing full L2 latency per chunk.
// Fix: k-split by relation. Block (m,r): out[m-tile] += h[:,r*128:+128] @ W_r
// = the round-4 PROVEN 128x128xK=128 gemm_body shape (hoisted B, one 32KB
// stage, one barrier, 64 MFMA/wave). 391x8 = 3128 blocks = 12.2 waves/SIMD.
// h read exactly once (102MB); W_r L2-hot (r=bid&7 -> per-XCD partition);
// accumulate with f32 atomicAdd (memory-side, no ordering assumption).
// out zeroed right before gemm3 (d_out scratch freed after agg).
// Front-end (prep/scans/scatter/agg) unchanged from round 7/8.

#define NBINS3    N_NODES                         // 50000
#define NB3       ((NBINS3 + 1023) / 1024)        // 49

// ---- ws layout (bytes): exactly the proven 109,462,464 budget
#define WS_H      0                               // h    : 50000 x 1024 f16 (102,400,000)
#define WS_WFT    102400000                       // WfT  : 128 x 1024 f16 (262,144)
#define WS_REC    102662144                       // rec  : N_EDGES uint2 (6,400,000)
#define WS_OFF    109062144                       // off  : 50001 i32 (pad 200,064)
#define WS_HIST   109262208                       // hist : 50000 i32 (200,000)
#define WS_BSUM   109462208                       // bsum : 49 i32 (pad 256)
#define WS_NEED   (size_t)109462464

// d_out scratch offsets (out = 25.6MB, dead until memset before gemm3)
#define DO_RANK   0                               // rank : N_EDGES i32 (3,200,000)
#define DO_FEATH  3200000                         // featH: 50000 x 128 f16 (12,800,000)

#define CONV_BLOCKS 3125                          // 800000 threads x 8 halfs = 6.4M elems
#define RANK_BLOCKS 3125                          // 800000 threads x 1 edge
#define PREP_BLOCKS (512 + CONV_BLOCKS + RANK_BLOCKS)   // 6762

// ---- prep: WfT transpose (512) + featH convert (3125) + rank capture (3125)
__global__ void prep_kernel(const float* __restrict__ rel_emb, half_t* __restrict__ WfT,
                            const float* __restrict__ feat, half_t* __restrict__ featH,
                            const int* __restrict__ dst, int* __restrict__ hist,
                            int* __restrict__ rank) {
    int b = blockIdx.x;
    if (b < 512) {                                 // 512*256 = 131072 = 8*128*128 exactly
        int t = b * 256 + threadIdx.x;             // t = r*16384 + k*128 + n
        int r = t >> 14, k = (t >> 7) & 127, n = t & 127;
        WfT[(size_t)n * 1024 + r * 128 + k] = (half_t)rel_emb[t];   // round-6 proven
    } else if (b < 512 + CONV_BLOCKS) {
        int t = (b - 512) * 256 + threadIdx.x;     // 0..799999, 8 halfs each
        const float* fb = feat + (size_t)t * 8;
        float4 v0 = *(const float4*)fb;
        float4 v1 = *(const float4*)(fb + 4);
        half8 hv;
        hv[0] = (half_t)v0.x; hv[1] = (half_t)v0.y; hv[2] = (half_t)v0.z; hv[3] = (half_t)v0.w;
        hv[4] = (half_t)v1.x; hv[5] = (half_t)v1.y; hv[6] = (half_t)v1.z; hv[7] = (half_t)v1.w;
        *(half8*)(featH + (size_t)t * 8) = hv;
    } else {
        int i = (b - 512 - CONV_BLOCKS) * 256 + threadIdx.x;   // < 800000 exactly
        rank[i] = atomicAdd(&hist[dst[i]], 1);     // round-4 proven rank capture
    }
}

// ---- scans (round-2..4 proven verbatim)
__global__ void scan1_kernel(const int* __restrict__ hist, int* __restrict__ bsum) {
    __shared__ int sh[256];
    int b = blockIdx.x, t = threadIdx.x;
    int i0 = b * 1024 + t * 4;
    int s = 0;
    #pragma unroll
    for (int j = 0; j < 4; j++) { int idx = i0 + j; if (idx < NBINS3) s += hist[idx]; }
    sh[t] = s; __syncthreads();
    for (int o = 128; o > 0; o >>= 1) { if (t < o) sh[t] += sh[t + o]; __syncthreads(); }
    if (t == 0) bsum[b] = sh[0];
}

__global__ void scan2_kernel(int* __restrict__ bsum, int* __restrict__ off) {
    __shared__ int sh[64];
    int t = threadIdx.x;
    int v = (t < NB3) ? bsum[t] : 0;
    sh[t] = v; __syncthreads();
    for (int o = 1; o < 64; o <<= 1) {
        int x = (t >= o) ? sh[t - o] : 0;
        __syncthreads();
        sh[t] += x;
        __syncthreads();
    }
    if (t < NB3) bsum[t] = sh[t] - v;
    if (t == 0) off[NBINS3] = N_EDGES;
}

__global__ void scan3_kernel(const int* __restrict__ hist, const int* __restrict__ boff,
                             int* __restrict__ off, int* __restrict__ cursors) {
    __shared__ int sh[256];
    int b = blockIdx.x, t = threadIdx.x;
    int i0 = b * 1024 + t * 4;
    int v[4]; int s = 0;
    #pragma unroll
    for (int j = 0; j < 4; j++) { int idx = i0 + j; v[j] = (idx < NBINS3) ? hist[idx] : 0; s += v[j]; }
    sh[t] = s; __syncthreads();
    for (int o = 1; o < 256; o <<= 1) {
        int x = (t >= o) ? sh[t - o] : 0;
        __syncthreads();
        sh[t] += x;
        __syncthreads();
    }
    int run = sh[t] - s + boff[b];
    #pragma unroll
    for (int j = 0; j < 4; j++) {
        int idx = i0 + j;
        if (idx < NBINS3) { off[idx] = run; cursors[idx] = run; }
        run += v[j];
    }
}

// ---- scatter: atomic-free (rank precomputed), fire-and-forget 8B records
__global__ __launch_bounds__(THREADS) void scatter_kernel(
    const int* __restrict__ dst, const int* __restrict__ src,
    const int* __restrict__ rel, const float* __restrict__ ew,
    const int* __restrict__ rank, const int* __restrict__ off,
    uint2* __restrict__ rec) {
    int i = blockIdx.x * 256 + threadIdx.x;        // 3125*256 = 800000 exactly
    int d = dst[i];
    int pos = off[d] + rank[i];
    uint2 v;
    v.x = (unsigned)(src[i] * 8 + rel[i]);         // src < 2^19, rel < 8
    v.y = __float_as_uint(ew[i]);
    rec[pos] = v;
}

// ---- agg: wave per dst; SEQUENTIAL rec reads; random featH reads (12.8MB region)
// accumulate h[8][128] in 16 f32 regs/lane (round-6 proven layout), MLP=4 edges.
__global__ __launch_bounds__(THREADS) void agg_kernel(
    const half_t* __restrict__ featH, const uint2* __restrict__ rec,
    const int* __restrict__ off, half_t* __restrict__ h) {
    int g = blockIdx.x * 4 + (threadIdx.x >> 6);   // 12500 blocks -> g < 50000
    int lane = threadIdx.x & 63;
    int beg = off[g], end = off[g + 1];

    float a0x = 0.f, a0y = 0.f, a1x = 0.f, a1y = 0.f;
    float a2x = 0.f, a2y = 0.f, a3x = 0.f, a3y = 0.f;
    float a4x = 0.f, a4y = 0.f, a5x = 0.f, a5y = 0.f;
    float a6x = 0.f, a6y = 0.f, a7x = 0.f, a7y = 0.f;

    const half_t* fb = featH + lane * 2;

#define ACCUM(RE, W, F) do {                                   \
        float wx_ = (W) * (float)(F)[0];                       \
        float wy_ = (W) * (float)(F)[1];                       \
        switch (RE) {                                          \
            case 0: a0x += wx_; a0y += wy_; break;             \
            case 1: a1x += wx_; a1y += wy_; break;             \
            case 2: a2x += wx_; a2y += wy_; break;             \
            case 3: a3x += wx_; a3y += wy_; break;             \
            case 4: a4x += wx_; a4y += wy_; break;             \
            case 5: a5x += wx_; a5y += wy_; break;             \
            case 6: a6x += wx_; a6y += wy_; break;             \
            default: a7x += wx_; a7y += wy_; break;            \
        } } while (0)

    int e = beg;
    for (; e + 4 <= end; e += 4) {                 // 4 independent featH reads in flight
        uint2 r0 = rec[e], r1 = rec[e + 1], r2 = rec[e + 2], r3 = rec[e + 3];
        half2v f0 = *(const half2v*)(fb + (size_t)(r0.x >> 3) * 128);
        half2v f1 = *(const half2v*)(fb + (size_t)(r1.x >> 3) * 128);
        half2v f2 = *(const half2v*)(fb + (size_t)(r2.x >> 3) * 128);
        half2v f3 = *(const half2v*)(fb + (size_t)(r3.x >> 3) * 128);
        ACCUM(r0.x & 7, __uint_as_float(r0.y), f0);
        ACCUM(r1.x & 7, __uint_as_float(r1.y), f1);
        ACCUM(r2.x & 7, __uint_as_float(r2.y), f2);
        ACCUM(r3.x & 7, __uint_as_float(r3.y), f3);
    }
    for (; e < end; e++) {
        uint2 r0 = rec[e];
        half2v f0 = *(const half2v*)(fb + (size_t)(r0.x >> 3) * 128);
        ACCUM(r0.x & 7, __uint_as_float(r0.y), f0);
    }
#undef ACCUM

    half_t* hb = h + (size_t)g * 1024 + lane * 2;  // round-6 proven store layout
    *(half2v*)(hb + 0 * 128) = (half2v){(half_t)a0x, (half_t)a0y};
    *(half2v*)(hb + 1 * 128) = (half2v){(half_t)a1x, (half_t)a1y};
    *(half2v*)(hb + 2 * 128) = (half2v){(half_t)a2x, (half_t)a2y};
    *(half2v*)(hb + 3 * 128) = (half2v){(half_t)a3x, (half_t)a3y};
    *(half2v*)(hb + 4 * 128) = (half2v){(half_t)a4x, (half_t)a4y};
    *(half2v*)(hb + 5 * 128) = (half2v){(half_t)a5x, (half_t)a5y};
    *(half2v*)(hb + 6 * 128) = (half2v){(half_t)a6x, (half_t)a6y};
    *(half2v*)(hb + 7 * 128) = (half2v){(half_t)a7x, (half_t)a7y};
}

// ---- gemm3 (round 9): k-split by relation, round-4-proven block shape.
// Block (m, r): out[m0..m0+127][0..127] += h[:, r*128:(r+1)*128] @ W_r.
//   a: Ws staged from WfT[c*1024 + r*128 + k] (rows = out cols, XOR swizzle)
//   b: h[node*1024 + r*128 + kk*32 + q*8]  (hoisted before stage)
//   C: out[node][nt*16+q*4+j] += acc[nt][ms][j]  via f32 atomicAdd
#define G3_MT ((N_NODES + 127) / 128)              // 391
#define G3_BLOCKS (G3_MT * 8)                      // 3128
template<bool GUARD>
__device__ __forceinline__ void gemm3_body(const half_t* __restrict__ h,
                                           const half_t* __restrict__ WfT,
                                           half_t* __restrict__ Ws,
                                           float* __restrict__ out,
                                           int m0, int r, int wave, int lane, int t) {
    const int q = lane >> 4, l16 = lane & 15;
    const int wm0 = m0 + wave * 32;

    // hoist b loads (h rows, already f16 -> no convert step)
    half8 bf[2][4];
    #pragma unroll
    for (int ms = 0; ms < 2; ms++) {
        int node = wm0 + ms * 16 + l16;
        bool ok = !GUARD || node < N_NODES;
        const half_t* hb = h + (size_t)node * 1024 + r * 128 + q * 8;
        #pragma unroll
        for (int kk = 0; kk < 4; kk++) {
            uint4 v = {0u, 0u, 0u, 0u};
            if (ok) v = *(const uint4*)(hb + kk * 32);
            bf[ms][kk] = *(half8*)&v;
        }
    }

    // stage W_r^T into LDS (rows = out cols, proven XOR swizzle)
    for (int i = t; i < 2048; i += THREADS) {
        int row = i >> 4, lc = i & 15;
        int phys = lc ^ (row & 7);
        *(uint4*)&Ws[row * 128 + phys * 8] =
            *(const uint4*)(WfT + (size_t)row * 1024 + r * 128 + lc * 8);
    }
    __syncthreads();

    floatx4 acc[8][2];
    #pragma unroll
    for (int nt = 0; nt < 8; nt++)
        #pragma unroll
        for (int ms = 0; ms < 2; ms++) acc[nt][ms] = (floatx4){0.f, 0.f, 0.f, 0.f};

    #pragma unroll
    for (int kk = 0; kk < 4; kk++)
        #pragma unroll
        for (int nt = 0; nt < 8; nt++) {
            int row = nt * 16 + l16;
            int phys = (kk * 4 + q) ^ (l16 & 7);
            half8 a = *(const half8*)(Ws + row * 128 + phys * 8);
            acc[nt][0] = __builtin_amdgcn_mfma_f32_16x16x32_f16(a, bf[0][kk], acc[nt][0], 0, 0, 0);
            acc[nt][1] = __builtin_amdgcn_mfma_f32_16x16x32_f16(a, bf[1][kk], acc[nt][1], 0, 0, 0);
        }

    // epilogue: f32 atomicAdd (8 r-blocks accumulate per tile; out pre-zeroed)
    #pragma unroll
    for (int ms = 0; ms < 2; ms++) {
        int node = wm0 + ms * 16 + l16;
        if (!GUARD || node < N_NODES) {
            float* ob = out + (size_t)node * 128 + q * 4;
            #pragma unroll
            for (int nt = 0; nt < 8; nt++) {
                atomicAdd(ob + nt * 16 + 0, acc[nt][ms][0]);
                atomicAdd(ob + nt * 16 + 1, acc[nt][ms][1]);
                atomicAdd(ob + nt * 16 + 2, acc[nt][ms][2]);
                atomicAdd(ob + nt * 16 + 3, acc[nt][ms][3]);
            }
        }
    }
}

__global__ __launch_bounds__(THREADS) void gemm3_kernel(
    const half_t* __restrict__ h, const half_t* __restrict__ WfT,
    float* __restrict__ out) {
    __shared__ half_t Ws[128 * 128];               // 32 KB
    const int bid = blockIdx.x;
    const int t = threadIdx.x;
    const int r = bid & 7;                         // same-r blocks share XCD (W_r L2-hot)
    const int mt = bid >> 3;                       // 0..390
    const int m0 = mt * 128;
    const int wave = t >> 6, lane = t & 63;
    if (m0 + 128 <= N_NODES)
        gemm3_body<false>(h, WfT, Ws, out, m0, r, wave, lane, t);
    else
        gemm3_body<true>(h, WfT, Ws, out, m0, r, wave, lane, t);
}

// ---- fallback (tiny ws): wave-per-edge direct with atomics
__global__ void naive_kernel(const float* __restrict__ feat, const float* __restrict__ rel_emb,
                             const float* __restrict__ ew, const int* __restrict__ src,
                             const int* __restrict__ dst, const int* __restrict__ rel,
                             float* __restrict__ out) {
    int wave = (blockIdx.x * blockDim.x + threadIdx.x) >> 6;
    int lane = threadIdx.x & 63;
    if (wave >= N_EDGES) return;
    const float* f = feat + (size_t)src[wave] * IN_DIM;
    const float* W = rel_emb + (size_t)rel[wave] * IN_DIM * OUT_DIM;
    float w = ew[wave];
    float a0 = 0.f, a1 = 0.f;
    for (int k = 0; k < IN_DIM; k++) {
        float fv = f[k];
        a0 += fv * W[k * OUT_DIM + lane];
        a1 += fv * W[k * OUT_DIM + 64 + lane];
    }
    int d = dst[wave];
    atomicAdd(&out[(size_t)d * OUT_DIM + lane], a0 * w);
    atomicAdd(&out[(size_t)d * OUT_DIM + 64 + lane], a1 * w);
}

extern "C" void kernel_launch(void* const* d_in, const int* in_sizes, int n_in,
                              void* d_out, int out_size, void* d_ws, size_t ws_size,
                              hipStream_t stream) {
    const float* feat    = (const float*)d_in[0];
    const float* rel_emb = (const float*)d_in[1];
    const float* ew      = (const float*)d_in[2];
    const int*   src     = (const int*)d_in[3];
    const int*   dst     = (const int*)d_in[4];
    const int*   rel     = (const int*)d_in[5];
    float* out = (float*)d_out;

    if (ws_size >= WS_NEED) {
        char* ws = (char*)d_ws;
        half_t* h    = (half_t*)(ws + WS_H);
        half_t* WfT  = (half_t*)(ws + WS_WFT);
        uint2*  rec  = (uint2*)(ws + WS_REC);
        int*    off  = (int*)(ws + WS_OFF);
        int*    hist = (int*)(ws + WS_HIST);
        int*    bsum = (int*)(ws + WS_BSUM);
        // d_out scratch (dead until memset below)
        int*    rank  = (int*)((char*)d_out + DO_RANK);
        half_t* featH = (half_t*)((char*)d_out + DO_FEATH);

        hipMemsetAsync(hist, 0, (size_t)NBINS3 * 4, stream);
        prep_kernel<<<PREP_BLOCKS, THREADS, 0, stream>>>(rel_emb, WfT, feat, featH,
                                                         dst, hist, rank);
        scan1_kernel<<<NB3, 256, 0, stream>>>(hist, bsum);
        scan2_kernel<<<1, 64, 0, stream>>>(bsum, off);
        scan3_kernel<<<NB3, 256, 0, stream>>>(hist, bsum, off, hist);  // cursors unused
        scatter_kernel<<<RANK_BLOCKS, THREADS, 0, stream>>>(dst, src, rel, ew,
                                                            rank, off, rec);
        agg_kernel<<<N_NODES / 4, THREADS, 0, stream>>>(featH, rec, off, h);
        // d_out scratch now dead -> zero out for atomic accumulation
        hipMemsetAsync(d_out, 0, (size_t)out_size * sizeof(float), stream);
        gemm3_kernel<<<G3_BLOCKS, THREADS, 0, stream>>>(h, WfT, out);
    } else {
        hipMemsetAsync(d_out, 0, (size_t)out_size * sizeof(float), stream);
        const long long total = (long long)N_EDGES * 64;
        const int blocks = (int)((total + THREADS - 1) / THREADS);
        naive_kernel<<<blocks, THREADS, 0, stream>>>(feat, rel_emb, ew, src, dst, rel, out);
    }
}

// Round 10
// 256.946 us; speedup vs baseline: 3.8068x; 3.8068x over previous
//
#include <hip/hip_runtime.h>
#include <stdint.h>

#define N_NODES   50000
#define N_EDGES   800000
#define IN_DIM    128
#define OUT_DIM   128
#define NUM_RELS  8
#define THREADS   256

typedef _Float16 half_t;
typedef _Float16 half2v __attribute__((ext_vector_type(2)));
typedef _Float16 half4v __attribute__((ext_vector_type(4)));
typedef _Float16 half8 __attribute__((ext_vector_type(8)));
typedef float floatx4 __attribute__((ext_vector_type(4)));

// ============ plan (round 10): k-split gemm3, IN-PLACE partials, no atomics ============
// Round-9 lesson: 51.2M f32 atomicAdds in the epilogue = 800MB RMW traffic,
// 824us. Fix: block (m,r) is the ONLY toucher of h[m-tile, r*128:+128] --
// reads are register-hoisted, so it can write its 128x128 partial p_r =
// h_r @ W_r IN-PLACE over that region (f16), via the round-4 PROVEN
// LDS-transpose coalesced epilogue (y2->h, n0->r*128). Then reduce_kernel:
// out[d][c] = sum_r h[d][r*128+c] (sequential, 128MB, ~20us).
// Front-end (prep/scans/scatter/agg) unchanged from rounds 7-9.

#define NBINS3    N_NODES                         // 50000
#define NB3       ((NBINS3 + 1023) / 1024)        // 49

// ---- ws layout (bytes): exactly the proven 109,462,464 budget
#define WS_H      0                               // h    : 50000 x 1024 f16 (102,400,000)
#define WS_WFT    102400000                       // WfT  : 128 x 1024 f16 (262,144)
#define WS_REC    102662144                       // rec  : N_EDGES uint2 (6,400,000)
#define WS_OFF    109062144                       // off  : 50001 i32 (pad 200,064)
#define WS_HIST   109262208                       // hist : 50000 i32 (200,000)
#define WS_BSUM   109462208                       // bsum : 49 i32 (pad 256)
#define WS_NEED   (size_t)109462464

// d_out scratch offsets (out = 25.6MB, dead until reduce writes it)
#define DO_RANK   0                               // rank : N_EDGES i32 (3,200,000)
#define DO_FEATH  3200000                         // featH: 50000 x 128 f16 (12,800,000)

#define CONV_BLOCKS 3125                          // 800000 threads x 8 halfs = 6.4M elems
#define RANK_BLOCKS 3125                          // 800000 threads x 1 edge
#define PREP_BLOCKS (512 + CONV_BLOCKS + RANK_BLOCKS)   // 6762

// ---- prep: WfT transpose (512) + featH convert (3125) + rank capture (3125)
__global__ void prep_kernel(const float* __restrict__ rel_emb, half_t* __restrict__ WfT,
                            const float* __restrict__ feat, half_t* __restrict__ featH,
                            const int* __restrict__ dst, int* __restrict__ hist,
                            int* __restrict__ rank) {
    int b = blockIdx.x;
    if (b < 512) {                                 // 512*256 = 131072 = 8*128*128 exactly
        int t = b * 256 + threadIdx.x;             // t = r*16384 + k*128 + n
        int r = t >> 14, k = (t >> 7) & 127, n = t & 127;
        WfT[(size_t)n * 1024 + r * 128 + k] = (half_t)rel_emb[t];   // round-6 proven
    } else if (b < 512 + CONV_BLOCKS) {
        int t = (b - 512) * 256 + threadIdx.x;     // 0..799999, 8 halfs each
        const float* fb = feat + (size_t)t * 8;
        float4 v0 = *(const float4*)fb;
        float4 v1 = *(const float4*)(fb + 4);
        half8 hv;
        hv[0] = (half_t)v0.x; hv[1] = (half_t)v0.y; hv[2] = (half_t)v0.z; hv[3] = (half_t)v0.w;
        hv[4] = (half_t)v1.x; hv[5] = (half_t)v1.y; hv[6] = (half_t)v1.z; hv[7] = (half_t)v1.w;
        *(half8*)(featH + (size_t)t * 8) = hv;
    } else {
        int i = (b - 512 - CONV_BLOCKS) * 256 + threadIdx.x;   // < 800000 exactly
        rank[i] = atomicAdd(&hist[dst[i]], 1);     // round-4 proven rank capture
    }
}

// ---- scans (round-2..4 proven verbatim)
__global__ void scan1_kernel(const int* __restrict__ hist, int* __restrict__ bsum) {
    __shared__ int sh[256];
    int b = blockIdx.x, t = threadIdx.x;
    int i0 = b * 1024 + t * 4;
    int s = 0;
    #pragma unroll
    for (int j = 0; j < 4; j++) { int idx = i0 + j; if (idx < NBINS3) s += hist[idx]; }
    sh[t] = s; __syncthreads();
    for (int o = 128; o > 0; o >>= 1) { if (t < o) sh[t] += sh[t + o]; __syncthreads(); }
    if (t == 0) bsum[b] = sh[0];
}

__global__ void scan2_kernel(int* __restrict__ bsum, int* __restrict__ off) {
    __shared__ int sh[64];
    int t = threadIdx.x;
    int v = (t < NB3) ? bsum[t] : 0;
    sh[t] = v; __syncthreads();
    for (int o = 1; o < 64; o <<= 1) {
        int x = (t >= o) ? sh[t - o] : 0;
        __syncthreads();
        sh[t] += x;
        __syncthreads();
    }
    if (t < NB3) bsum[t] = sh[t] - v;
    if (t == 0) off[NBINS3] = N_EDGES;
}

__global__ void scan3_kernel(const int* __restrict__ hist, const int* __restrict__ boff,
                             int* __restrict__ off, int* __restrict__ cursors) {
    __shared__ int sh[256];
    int b = blockIdx.x, t = threadIdx.x;
    int i0 = b * 1024 + t * 4;
    int v[4]; int s = 0;
    #pragma unroll
    for (int j = 0; j < 4; j++) { int idx = i0 + j; v[j] = (idx < NBINS3) ? hist[idx] : 0; s += v[j]; }
    sh[t] = s; __syncthreads();
    for (int o = 1; o < 256; o <<= 1) {
        int x = (t >= o) ? sh[t - o] : 0;
        __syncthreads();
        sh[t] += x;
        __syncthreads();
    }
    int run = sh[t] - s + boff[b];
    #pragma unroll
    for (int j = 0; j < 4; j++) {
        int idx = i0 + j;
        if (idx < NBINS3) { off[idx] = run; cursors[idx] = run; }
        run += v[j];
    }
}

// ---- scatter: atomic-free (rank precomputed), fire-and-forget 8B records
__global__ __launch_bounds__(THREADS) void scatter_kernel(
    const int* __restrict__ dst, const int* __restrict__ src,
    const int* __restrict__ rel, const float* __restrict__ ew,
    const int* __restrict__ rank, const int* __restrict__ off,
    uint2* __restrict__ rec) {
    int i = blockIdx.x * 256 + threadIdx.x;        // 3125*256 = 800000 exactly
    int d = dst[i];
    int pos = off[d] + rank[i];
    uint2 v;
    v.x = (unsigned)(src[i] * 8 + rel[i]);         // src < 2^19, rel < 8
    v.y = __float_as_uint(ew[i]);
    rec[pos] = v;
}

// ---- agg: wave per dst; SEQUENTIAL rec reads; random featH reads (12.8MB region)
// accumulate h[8][128] in 16 f32 regs/lane (round-6 proven layout), MLP=4 edges.
__global__ __launch_bounds__(THREADS) void agg_kernel(
    const half_t* __restrict__ featH, const uint2* __restrict__ rec,
    const int* __restrict__ off, half_t* __restrict__ h) {
    int g = blockIdx.x * 4 + (threadIdx.x >> 6);   // 12500 blocks -> g < 50000
    int lane = threadIdx.x & 63;
    int beg = off[g], end = off[g + 1];

    float a0x = 0.f, a0y = 0.f, a1x = 0.f, a1y = 0.f;
    float a2x = 0.f, a2y = 0.f, a3x = 0.f, a3y = 0.f;
    float a4x = 0.f, a4y = 0.f, a5x = 0.f, a5y = 0.f;
    float a6x = 0.f, a6y = 0.f, a7x = 0.f, a7y = 0.f;

    const half_t* fb = featH + lane * 2;

#define ACCUM(RE, W, F) do {                                   \
        float wx_ = (W) * (float)(F)[0];                       \
        float wy_ = (W) * (float)(F)[1];                       \
        switch (RE) {                                          \
            case 0: a0x += wx_; a0y += wy_; break;             \
            case 1: a1x += wx_; a1y += wy_; break;             \
            case 2: a2x += wx_; a2y += wy_; break;             \
            case 3: a3x += wx_; a3y += wy_; break;             \
            case 4: a4x += wx_; a4y += wy_; break;             \
            case 5: a5x += wx_; a5y += wy_; break;             \
            case 6: a6x += wx_; a6y += wy_; break;             \
            default: a7x += wx_; a7y += wy_; break;            \
        } } while (0)

    int e = beg;
    for (; e + 4 <= end; e += 4) {                 // 4 independent featH reads in flight
        uint2 r0 = rec[e], r1 = rec[e + 1], r2 = rec[e + 2], r3 = rec[e + 3];
        half2v f0 = *(const half2v*)(fb + (size_t)(r0.x >> 3) * 128);
        half2v f1 = *(const half2v*)(fb + (size_t)(r1.x >> 3) * 128);
        half2v f2 = *(const half2v*)(fb + (size_t)(r2.x >> 3) * 128);
        half2v f3 = *(const half2v*)(fb + (size_t)(r3.x >> 3) * 128);
        ACCUM(r0.x & 7, __uint_as_float(r0.y), f0);
        ACCUM(r1.x & 7, __uint_as_float(r1.y), f1);
        ACCUM(r2.x & 7, __uint_as_float(r2.y), f2);
        ACCUM(r3.x & 7, __uint_as_float(r3.y), f3);
    }
    for (; e < end; e++) {
        uint2 r0 = rec[e];
        half2v f0 = *(const half2v*)(fb + (size_t)(r0.x >> 3) * 128);
        ACCUM(r0.x & 7, __uint_as_float(r0.y), f0);
    }
#undef ACCUM

    half_t* hb = h + (size_t)g * 1024 + lane * 2;  // round-6 proven store layout
    *(half2v*)(hb + 0 * 128) = (half2v){(half_t)a0x, (half_t)a0y};
    *(half2v*)(hb + 1 * 128) = (half2v){(half_t)a1x, (half_t)a1y};
    *(half2v*)(hb + 2 * 128) = (half2v){(half_t)a2x, (half_t)a2y};
    *(half2v*)(hb + 3 * 128) = (half2v){(half_t)a3x, (half_t)a3y};
    *(half2v*)(hb + 4 * 128) = (half2v){(half_t)a4x, (half_t)a4y};
    *(half2v*)(hb + 5 * 128) = (half2v){(half_t)a5x, (half_t)a5y};
    *(half2v*)(hb + 6 * 128) = (half2v){(half_t)a6x, (half_t)a6y};
    *(half2v*)(hb + 7 * 128) = (half2v){(half_t)a7x, (half_t)a7y};
}

// ---- gemm3 (round 10): k-split by relation, IN-PLACE f16 partial, no atomics.
// Block (m, r): h[m0:+128, r*128:+128] <- h[m0:+128, r*128:+128] @ W_r.
// Sole toucher of that region; reads hoisted to registers before any write.
// Epilogue = round-4 PROVEN LDS-transpose + coalesced uint4 stores.
#define G3_MT ((N_NODES + 127) / 128)              // 391
#define G3_BLOCKS (G3_MT * 8)                      // 3128
template<bool GUARD>
__device__ __forceinline__ void gemm3_body(half_t* __restrict__ h,
                                           const half_t* __restrict__ WfT,
                                           half_t* __restrict__ Ws,
                                           int m0, int r, int wave, int lane, int t) {
    const int q = lane >> 4, l16 = lane & 15;
    const int wm0 = m0 + wave * 32;

    // hoist b loads (h rows; ALL h reads complete before MFMA/epilogue)
    half8 bf[2][4];
    #pragma unroll
    for (int ms = 0; ms < 2; ms++) {
        int node = wm0 + ms * 16 + l16;
        bool ok = !GUARD || node < N_NODES;
        const half_t* hb = h + (size_t)node * 1024 + r * 128 + q * 8;
        #pragma unroll
        for (int kk = 0; kk < 4; kk++) {
            uint4 v = {0u, 0u, 0u, 0u};
            if (ok) v = *(const uint4*)(hb + kk * 32);
            bf[ms][kk] = *(half8*)&v;
        }
    }

    // stage W_r^T into LDS (rows = out cols, proven XOR swizzle)
    for (int i = t; i < 2048; i += THREADS) {
        int row = i >> 4, lc = i & 15;
        int phys = lc ^ (row & 7);
        *(uint4*)&Ws[row * 128 + phys * 8] =
            *(const uint4*)(WfT + (size_t)row * 1024 + r * 128 + lc * 8);
    }
    __syncthreads();

    floatx4 acc[8][2];
    #pragma unroll
    for (int nt = 0; nt < 8; nt++)
        #pragma unroll
        for (int ms = 0; ms < 2; ms++) acc[nt][ms] = (floatx4){0.f, 0.f, 0.f, 0.f};

    #pragma unroll
    for (int kk = 0; kk < 4; kk++)
        #pragma unroll
        for (int nt = 0; nt < 8; nt++) {
            int row = nt * 16 + l16;
            int phys = (kk * 4 + q) ^ (l16 & 7);
            half8 a = *(const half8*)(Ws + row * 128 + phys * 8);
            acc[nt][0] = __builtin_amdgcn_mfma_f32_16x16x32_f16(a, bf[0][kk], acc[nt][0], 0, 0, 0);
            acc[nt][1] = __builtin_amdgcn_mfma_f32_16x16x32_f16(a, bf[1][kk], acc[nt][1], 0, 0, 0);
        }

    // epilogue: transpose through Ws, coalesced uint4 stores (round-4 proven)
    __syncthreads();
    #pragma unroll
    for (int nt = 0; nt < 8; nt++)
        #pragma unroll
        for (int ms = 0; ms < 2; ms++) {
            int nl = wave * 32 + ms * 16 + l16;
            int c  = nt * 4 + q;
            int p  = (c + nl) & 31;
            half4v hv;
            hv[0] = (half_t)acc[nt][ms][0]; hv[1] = (half_t)acc[nt][ms][1];
            hv[2] = (half_t)acc[nt][ms][2]; hv[3] = (half_t)acc[nt][ms][3];
            *(half4v*)(Ws + nl * 128 + p * 4) = hv;
        }
    #pragma unroll
    for (int i = 0; i < 8; i++) {
        int nl  = wave * 32 + i * 4 + (lane >> 4);
        int c16 = lane & 15;
        int p0 = (2 * c16 + nl) & 31;
        int p1 = (2 * c16 + 1 + nl) & 31;
        uint2 lo = *(const uint2*)(Ws + nl * 128 + p0 * 4);
        uint2 hi = *(const uint2*)(Ws + nl * 128 + p1 * 4);
        int node = m0 + nl;
        if (!GUARD || node < N_NODES) {
            uint4 v; v.x = lo.x; v.y = lo.y; v.z = hi.x; v.w = hi.y;
            *(uint4*)(h + (size_t)node * 1024 + r * 128 + c16 * 8) = v;
        }
    }
}

__global__ __launch_bounds__(THREADS) void gemm3_kernel(
    half_t* __restrict__ h, const half_t* __restrict__ WfT) {
    __shared__ half_t Ws[128 * 128];               // 32 KB -> 5 blocks/CU
    const int bid = blockIdx.x;
    const int t = threadIdx.x;
    const int r = bid & 7;                         // same-r blocks share XCD (W_r L2-hot)
    const int mt = bid >> 3;                       // 0..390
    const int m0 = mt * 128;
    const int wave = t >> 6, lane = t & 63;
    if (m0 + 128 <= N_NODES)
        gemm3_body<false>(h, WfT, Ws, m0, r, wave, lane, t);
    else
        gemm3_body<true>(h, WfT, Ws, m0, r, wave, lane, t);
}

// ---- reduce: out[d][c] = sum_r h[d][r*128+c]; coalesced half2 reads, MLP=8
__global__ __launch_bounds__(THREADS) void reduce_kernel(
    const half_t* __restrict__ h, float* __restrict__ out) {
    int g = blockIdx.x * 4 + (threadIdx.x >> 6);   // 12500 blocks -> g < 50000
    int lane = threadIdx.x & 63;
    const half_t* hb = h + (size_t)g * 1024 + lane * 2;
    half2v v0 = *(const half2v*)(hb + 0 * 128);
    half2v v1 = *(const half2v*)(hb + 1 * 128);
    half2v v2 = *(const half2v*)(hb + 2 * 128);
    half2v v3 = *(const half2v*)(hb + 3 * 128);
    half2v v4 = *(const half2v*)(hb + 4 * 128);
    half2v v5 = *(const half2v*)(hb + 5 * 128);
    half2v v6 = *(const half2v*)(hb + 6 * 128);
    half2v v7 = *(const half2v*)(hb + 7 * 128);
    float sx = (float)v0[0] + (float)v1[0] + (float)v2[0] + (float)v3[0]
             + (float)v4[0] + (float)v5[0] + (float)v6[0] + (float)v7[0];
    float sy = (float)v0[1] + (float)v1[1] + (float)v2[1] + (float)v3[1]
             + (float)v4[1] + (float)v5[1] + (float)v6[1] + (float)v7[1];
    float2 o; o.x = sx; o.y = sy;
    *(float2*)(out + (size_t)g * 128 + lane * 2) = o;
}

// ---- fallback (tiny ws): wave-per-edge direct with atomics
__global__ void naive_kernel(const float* __restrict__ feat, const float* __restrict__ rel_emb,
                             const float* __restrict__ ew, const int* __restrict__ src,
                             const int* __restrict__ dst, const int* __restrict__ rel,
                             float* __restrict__ out) {
    int wave = (blockIdx.x * blockDim.x + threadIdx.x) >> 6;
    int lane = threadIdx.x & 63;
    if (wave >= N_EDGES) return;
    const float* f = feat + (size_t)src[wave] * IN_DIM;
    const float* W = rel_emb + (size_t)rel[wave] * IN_DIM * OUT_DIM;
    float w = ew[wave];
    float a0 = 0.f, a1 = 0.f;
    for (int k = 0; k < IN_DIM; k++) {
        float fv = f[k];
        a0 += fv * W[k * OUT_DIM + lane];
        a1 += fv * W[k * OUT_DIM + 64 + lane];
    }
    int d = dst[wave];
    atomicAdd(&out[(size_t)d * OUT_DIM + lane], a0 * w);
    atomicAdd(&out[(size_t)d * OUT_DIM + 64 + lane], a1 * w);
}

extern "C" void kernel_launch(void* const* d_in, const int* in_sizes, int n_in,
                              void* d_out, int out_size, void* d_ws, size_t ws_size,
                              hipStream_t stream) {
    const float* feat    = (const float*)d_in[0];
    const float* rel_emb = (const float*)d_in[1];
    const float* ew      = (const float*)d_in[2];
    const int*   src     = (const int*)d_in[3];
    const int*   dst     = (const int*)d_in[4];
    const int*   rel     = (const int*)d_in[5];
    float* out = (float*)d_out;

    if (ws_size >= WS_NEED) {
        char* ws = (char*)d_ws;
        half_t* h    = (half_t*)(ws + WS_H);
        half_t* WfT  = (half_t*)(ws + WS_WFT);
        uint2*  rec  = (uint2*)(ws + WS_REC);
        int*    off  = (int*)(ws + WS_OFF);
        int*    hist = (int*)(ws + WS_HIST);
        int*    bsum = (int*)(ws + WS_BSUM);
        // d_out scratch (dead until reduce writes out)
        int*    rank  = (int*)((char*)d_out + DO_RANK);
        half_t* featH = (half_t*)((char*)d_out + DO_FEATH);

        hipMemsetAsync(hist, 0, (size_t)NBINS3 * 4, stream);
        prep_kernel<<<PREP_BLOCKS, THREADS, 0, stream>>>(rel_emb, WfT, feat, featH,
                                                         dst, hist, rank);
        scan1_kernel<<<NB3, 256, 0, stream>>>(hist, bsum);
        scan2_kernel<<<1, 64, 0, stream>>>(bsum, off);
        scan3_kernel<<<NB3, 256, 0, stream>>>(hist, bsum, off, hist);  // cursors unused
        scatter_kernel<<<RANK_BLOCKS, THREADS, 0, stream>>>(dst, src, rel, ew,
                                                            rank, off, rec);
        agg_kernel<<<N_NODES / 4, THREADS, 0, stream>>>(featH, rec, off, h);
        gemm3_kernel<<<G3_BLOCKS, THREADS, 0, stream>>>(h, WfT);       // in-place partials
        reduce_kernel<<<N_NODES / 4, THREADS, 0, stream>>>(h, out);
    } else {
        hipMemsetAsync(d_out, 0, (size_t)out_size * sizeof(float), stream);
        const long long total = (long long)N_EDGES * 64;
        const int blocks = (int)((total + THREADS - 1) / THREADS);
        naive_kernel<<<blocks, THREADS, 0, stream>>>(feat, rel_emb, ew, src, dst, rel, out);
    }
}

// Round 11
// 256.235 us; speedup vs baseline: 3.8174x; 1.0028x over previous
//
#include <hip/hip_runtime.h>
#include <stdint.h>

#define N_NODES   50000
#define N_EDGES   800000
#define IN_DIM    128
#define OUT_DIM   128
#define NUM_RELS  8
#define THREADS   256

typedef _Float16 half_t;
typedef _Float16 half2v __attribute__((ext_vector_type(2)));
typedef _Float16 half4v __attribute__((ext_vector_type(4)));
typedef _Float16 half8 __attribute__((ext_vector_type(8)));
typedef float floatx4 __attribute__((ext_vector_type(4)));

// ============ plan (round 11) ============
// Round-10 counters: prep 57us, WRITE 42.6MB vs 16.3MB useful -> ~26MB of
// hist-line cross-XCD migration writebacks (800k device atomics ping-pong
// the 200KB hist between XCD L2s).
// Fix 1: XCD-SHARDED hist8[8][50000]; shard = bid&7 (block's XCD under RR).
//   Same-shard atomics come from one XCD -> no migration. Shard for edge i
//   is pure arithmetic ((RANK_BASE+(i>>8))&7) -> correctness independent of
//   actual XCD mapping. Scans sum 8 planes; off8[s][d] gives scatter base.
// Fix 2: r-pair gemm3: block (m,rp) computes h_r0@W_r0 + h_r1@W_r1 in f32,
//   writes ONE f16 partial (128 cols) -> gemm3 writes 51MB (was 102),
//   reduce reads 51MB (was 102). 1564 blocks = 6.1 waves/SIMD (no round-8
//   starvation). Pair summed in f32 before f16 rounding -> precision same/better.

#define NBINS3    N_NODES                         // 50000
#define NB3       ((NBINS3 + 1023) / 1024)        // 49

// ---- ws layout (bytes): proven 109,462,464 budget
#define WS_H      0                               // h    : 50000 x 1024 f16 (102,400,000)
#define WS_WFT    102400000                       // WfT  : 128 x 1024 f16 (262,144)
#define WS_REC    102662144                       // rec  : N_EDGES uint2 (6,400,000)
#define WS_OFF    109062144                       // off  : 50001 i32 (pad 200,064)
#define WS_HIST   109262208                       // (unused this round)
#define WS_BSUM   109462208                       // bsum : 49 i32 (pad 256)
#define WS_NEED   (size_t)109462464

// d_out scratch (25.6MB, dead until reduce): rank + featH + hist8 + off8
#define DO_RANK   0                               // rank : N_EDGES i32 (3,200,000)
#define DO_FEATH  3200000                         // featH: 50000 x 128 f16 (12,800,000)
#define DO_HIST8  16000000                        // hist8: 8 x 50000 i32 (1,600,000)
#define DO_OFF8   17600000                        // off8 : 8 x 50000 i32 (1,600,000)
                                                  // ends 19,200,000 < 25,600,000 OK

#define CONV_BLOCKS 3125                          // 800000 threads x 8 halfs
#define RANK_BLOCKS 3125                          // 800000 threads x 1 edge
#define RANK_BASE   (512 + CONV_BLOCKS)           // 3637
#define PREP_BLOCKS (RANK_BASE + RANK_BLOCKS)     // 6762

// ---- prep: WfT transpose (512) + featH convert (3125) + sharded rank (3125)
__global__ void prep_kernel(const float* __restrict__ rel_emb, half_t* __restrict__ WfT,
                            const float* __restrict__ feat, half_t* __restrict__ featH,
                            const int* __restrict__ dst, int* __restrict__ hist8,
                            int* __restrict__ rank) {
    int b = blockIdx.x;
    if (b < 512) {                                 // 8*128*128 exactly
        int t = b * 256 + threadIdx.x;             // t = r*16384 + k*128 + n
        int r = t >> 14, k = (t >> 7) & 127, n = t & 127;
        WfT[(size_t)n * 1024 + r * 128 + k] = (half_t)rel_emb[t];
    } else if (b < RANK_BASE) {
        int t = (b - 512) * 256 + threadIdx.x;     // 0..799999, 8 halfs each
        const float* fb = feat + (size_t)t * 8;
        float4 v0 = *(const float4*)fb;
        float4 v1 = *(const float4*)(fb + 4);
        half8 hv;
        hv[0] = (half_t)v0.x; hv[1] = (half_t)v0.y; hv[2] = (half_t)v0.z; hv[3] = (half_t)v0.w;
        hv[4] = (half_t)v1.x; hv[5] = (half_t)v1.y; hv[6] = (half_t)v1.z; hv[7] = (half_t)v1.w;
        *(half8*)(featH + (size_t)t * 8) = hv;
    } else {
        int i = (b - RANK_BASE) * 256 + threadIdx.x;   // < 800000 exactly
        int s = b & 7;                             // this block's XCD shard (RR assumption)
        rank[i] = atomicAdd(&hist8[s * NBINS3 + dst[i]], 1);
    }
}

// ---- scan1: bsum[b] = sum over 1024 dsts of 8-plane hist
__global__ void scan1_kernel(const int* __restrict__ hist8, int* __restrict__ bsum) {
    __shared__ int sh[256];
    int b = blockIdx.x, t = threadIdx.x;
    int i0 = b * 1024 + t * 4;
    int s = 0;
    #pragma unroll
    for (int j = 0; j < 4; j++) {
        int idx = i0 + j;
        if (idx < NBINS3)
            #pragma unroll
            for (int x = 0; x < 8; x++) s += hist8[x * NBINS3 + idx];
    }
    sh[t] = s; __syncthreads();
    for (int o = 128; o > 0; o >>= 1) { if (t < o) sh[t] += sh[t + o]; __syncthreads(); }
    if (t == 0) bsum[b] = sh[0];
}

__global__ void scan2_kernel(int* __restrict__ bsum, int* __restrict__ off) {
    __shared__ int sh[64];
    int t = threadIdx.x;
    int v = (t < NB3) ? bsum[t] : 0;
    sh[t] = v; __syncthreads();
    for (int o = 1; o < 64; o <<= 1) {
        int x = (t >= o) ? sh[t - o] : 0;
        __syncthreads();
        sh[t] += x;
        __syncthreads();
    }
    if (t < NB3) bsum[t] = sh[t] - v;
    if (t == 0) off[NBINS3] = N_EDGES;
}

// ---- scan3: off[d] + per-shard bases off8[x][d]
__global__ void scan3_kernel(const int* __restrict__ hist8, const int* __restrict__ boff,
                             int* __restrict__ off, int* __restrict__ off8) {
    __shared__ int sh[256];
    int b = blockIdx.x, t = threadIdx.x;
    int i0 = b * 1024 + t * 4;
    int c[4][8]; int v[4]; int s = 0;
    #pragma unroll
    for (int j = 0; j < 4; j++) {
        int idx = i0 + j; int tot = 0;
        #pragma unroll
        for (int x = 0; x < 8; x++) {
            int cv = (idx < NBINS3) ? hist8[x * NBINS3 + idx] : 0;
            c[j][x] = cv; tot += cv;
        }
        v[j] = tot; s += tot;
    }
    sh[t] = s; __syncthreads();
    for (int o = 1; o < 256; o <<= 1) {
        int x = (t >= o) ? sh[t - o] : 0;
        __syncthreads();
        sh[t] += x;
        __syncthreads();
    }
    int run = sh[t] - s + boff[b];
    #pragma unroll
    for (int j = 0; j < 4; j++) {
        int idx = i0 + j;
        if (idx < NBINS3) {
            off[idx] = run;
            int rx = run;
            #pragma unroll
            for (int x = 0; x < 8; x++) { off8[x * NBINS3 + idx] = rx; rx += c[j][x]; }
        }
        run += v[j];
    }
}

// ---- scatter: atomic-free; shard recomputed from i (matches prep's b&7)
__global__ __launch_bounds__(THREADS) void scatter_kernel(
    const int* __restrict__ dst, const int* __restrict__ src,
    const int* __restrict__ rel, const float* __restrict__ ew,
    const int* __restrict__ rank, const int* __restrict__ off8,
    uint2* __restrict__ rec) {
    int i = blockIdx.x * 256 + threadIdx.x;        // 3125*256 = 800000 exactly
    int d = dst[i];
    int s = (RANK_BASE + (i >> 8)) & 7;            // == prep rank-block's bid&7
    int pos = off8[s * NBINS3 + d] + rank[i];
    uint2 v;
    v.x = (unsigned)(src[i] * 8 + rel[i]);         // src < 2^19, rel < 8
    v.y = __float_as_uint(ew[i]);
    rec[pos] = v;
}

// ---- agg: wave per dst; sequential rec reads; random featH reads (12.8MB)
__global__ __launch_bounds__(THREADS) void agg_kernel(
    const half_t* __restrict__ featH, const uint2* __restrict__ rec,
    const int* __restrict__ off, half_t* __restrict__ h) {
    int g = blockIdx.x * 4 + (threadIdx.x >> 6);   // 12500 blocks -> g < 50000
    int lane = threadIdx.x & 63;
    int beg = off[g], end = off[g + 1];

    float a0x = 0.f, a0y = 0.f, a1x = 0.f, a1y = 0.f;
    float a2x = 0.f, a2y = 0.f, a3x = 0.f, a3y = 0.f;
    float a4x = 0.f, a4y = 0.f, a5x = 0.f, a5y = 0.f;
    float a6x = 0.f, a6y = 0.f, a7x = 0.f, a7y = 0.f;

    const half_t* fb = featH + lane * 2;

#define ACCUM(RE, W, F) do {                                   \
        float wx_ = (W) * (float)(F)[0];                       \
        float wy_ = (W) * (float)(F)[1];                       \
        switch (RE) {                                          \
            case 0: a0x += wx_; a0y += wy_; break;             \
            case 1: a1x += wx_; a1y += wy_; break;             \
            case 2: a2x += wx_; a2y += wy_; break;             \
            case 3: a3x += wx_; a3y += wy_; break;             \
            case 4: a4x += wx_; a4y += wy_; break;             \
            case 5: a5x += wx_; a5y += wy_; break;             \
            case 6: a6x += wx_; a6y += wy_; break;             \
            default: a7x += wx_; a7y += wy_; break;            \
        } } while (0)

    int e = beg;
    for (; e + 4 <= end; e += 4) {
        uint2 r0 = rec[e], r1 = rec[e + 1], r2 = rec[e + 2], r3 = rec[e + 3];
        half2v f0 = *(const half2v*)(fb + (size_t)(r0.x >> 3) * 128);
        half2v f1 = *(const half2v*)(fb + (size_t)(r1.x >> 3) * 128);
        half2v f2 = *(const half2v*)(fb + (size_t)(r2.x >> 3) * 128);
        half2v f3 = *(const half2v*)(fb + (size_t)(r3.x >> 3) * 128);
        ACCUM(r0.x & 7, __uint_as_float(r0.y), f0);
        ACCUM(r1.x & 7, __uint_as_float(r1.y), f1);
        ACCUM(r2.x & 7, __uint_as_float(r2.y), f2);
        ACCUM(r3.x & 7, __uint_as_float(r3.y), f3);
    }
    for (; e < end; e++) {
        uint2 r0 = rec[e];
        half2v f0 = *(const half2v*)(fb + (size_t)(r0.x >> 3) * 128);
        ACCUM(r0.x & 7, __uint_as_float(r0.y), f0);
    }
#undef ACCUM

    half_t* hb = h + (size_t)g * 1024 + lane * 2;
    *(half2v*)(hb + 0 * 128) = (half2v){(half_t)a0x, (half_t)a0y};
    *(half2v*)(hb + 1 * 128) = (half2v){(half_t)a1x, (half_t)a1y};
    *(half2v*)(hb + 2 * 128) = (half2v){(half_t)a2x, (half_t)a2y};
    *(half2v*)(hb + 3 * 128) = (half2v){(half_t)a3x, (half_t)a3y};
    *(half2v*)(hb + 4 * 128) = (half2v){(half_t)a4x, (half_t)a4y};
    *(half2v*)(hb + 5 * 128) = (half2v){(half_t)a5x, (half_t)a5y};
    *(half2v*)(hb + 6 * 128) = (half2v){(half_t)a6x, (half_t)a6y};
    *(half2v*)(hb + 7 * 128) = (half2v){(half_t)a7x, (half_t)a7y};
}

// ---- gemm3 (round 11): r-PAIR k-split, in-place f16 partial, no atomics.
// Block (m, rp): p = h_r0 @ W_r0 + h_r1 @ W_r1 (f32 acc), write 128-col f16
// partial into h[m-tile, rp*256:+128]. Sole toucher; all h reads hoisted to
// registers before any h write. Epilogue = round-4 proven LDS transpose.
#define G3_MT ((N_NODES + 127) / 128)              // 391
#define G3_BLOCKS (G3_MT * 4)                      // 1564
template<bool GUARD>
__device__ __forceinline__ void gemm3_body(half_t* __restrict__ h,
                                           const half_t* __restrict__ WfT,
                                           half_t* __restrict__ Ws,
                                           int m0, int rp, int wave, int lane, int t) {
    const int q = lane >> 4, l16 = lane & 15;
    const int wm0 = m0 + wave * 32;
    const int r0 = rp * 2, r1 = rp * 2 + 1;

    // hoist ALL h reads (both rel slots) before any staging/writes
    half8 bf0[2][4], bf1[2][4];
    #pragma unroll
    for (int ms = 0; ms < 2; ms++) {
        int node = wm0 + ms * 16 + l16;
        bool ok = !GUARD || node < N_NODES;
        const half_t* hb0 = h + (size_t)node * 1024 + r0 * 128 + q * 8;
        const half_t* hb1 = h + (size_t)node * 1024 + r1 * 128 + q * 8;
        #pragma unroll
        for (int kk = 0; kk < 4; kk++) {
            uint4 v0 = {0u, 0u, 0u, 0u}, v1 = {0u, 0u, 0u, 0u};
            if (ok) { v0 = *(const uint4*)(hb0 + kk * 32); v1 = *(const uint4*)(hb1 + kk * 32); }
            bf0[kk >> 2][kk] = bf0[0][kk];          // (placeholder removed below)
            bf0[ms][kk] = *(half8*)&v0;
            bf1[ms][kk] = *(half8*)&v1;
        }
    }

    floatx4 acc[8][2];
    #pragma unroll
    for (int nt = 0; nt < 8; nt++)
        #pragma unroll
        for (int ms = 0; ms < 2; ms++) acc[nt][ms] = (floatx4){0.f, 0.f, 0.f, 0.f};

    // ---- chunk r0
    for (int i = t; i < 2048; i += THREADS) {
        int row = i >> 4, lc = i & 15;
        int phys = lc ^ (row & 7);
        *(uint4*)&Ws[row * 128 + phys * 8] =
            *(const uint4*)(WfT + (size_t)row * 1024 + r0 * 128 + lc * 8);
    }
    __syncthreads();
    #pragma unroll
    for (int kk = 0; kk < 4; kk++)
        #pragma unroll
        for (int nt = 0; nt < 8; nt++) {
            int row = nt * 16 + l16;
            int phys = (kk * 4 + q) ^ (l16 & 7);
            half8 a = *(const half8*)(Ws + row * 128 + phys * 8);
            acc[nt][0] = __builtin_amdgcn_mfma_f32_16x16x32_f16(a, bf0[0][kk], acc[nt][0], 0, 0, 0);
            acc[nt][1] = __builtin_amdgcn_mfma_f32_16x16x32_f16(a, bf0[1][kk], acc[nt][1], 0, 0, 0);
        }
    __syncthreads();                               // before Ws overwrite

    // ---- chunk r1
    for (int i = t; i < 2048; i += THREADS) {
        int row = i >> 4, lc = i & 15;
        int phys = lc ^ (row & 7);
        *(uint4*)&Ws[row * 128 + phys * 8] =
            *(const uint4*)(WfT + (size_t)row * 1024 + r1 * 128 + lc * 8);
    }
    __syncthreads();
    #pragma unroll
    for (int kk = 0; kk < 4; kk++)
        #pragma unroll
        for (int nt = 0; nt < 8; nt++) {
            int row = nt * 16 + l16;
            int phys = (kk * 4 + q) ^ (l16 & 7);
            half8 a = *(const half8*)(Ws + row * 128 + phys * 8);
            acc[nt][0] = __builtin_amdgcn_mfma_f32_16x16x32_f16(a, bf1[0][kk], acc[nt][0], 0, 0, 0);
            acc[nt][1] = __builtin_amdgcn_mfma_f32_16x16x32_f16(a, bf1[1][kk], acc[nt][1], 0, 0, 0);
        }

    // epilogue: transpose through Ws, coalesced uint4 stores (proven)
    __syncthreads();
    #pragma unroll
    for (int nt = 0; nt < 8; nt++)
        #pragma unroll
        for (int ms = 0; ms < 2; ms++) {
            int nl = wave * 32 + ms * 16 + l16;
            int c  = nt * 4 + q;
            int p  = (c + nl) & 31;
            half4v hv;
            hv[0] = (half_t)acc[nt][ms][0]; hv[1] = (half_t)acc[nt][ms][1];
            hv[2] = (half_t)acc[nt][ms][2]; hv[3] = (half_t)acc[nt][ms][3];
            *(half4v*)(Ws + nl * 128 + p * 4) = hv;
        }
    #pragma unroll
    for (int i = 0; i < 8; i++) {
        int nl  = wave * 32 + i * 4 + (lane >> 4);
        int c16 = lane & 15;
        int p0 = (2 * c16 + nl) & 31;
        int p1 = (2 * c16 + 1 + nl) & 31;
        uint2 lo = *(const uint2*)(Ws + nl * 128 + p0 * 4);
        uint2 hi = *(const uint2*)(Ws + nl * 128 + p1 * 4);
        int node = m0 + nl;
        if (!GUARD || node < N_NODES) {
            uint4 v; v.x = lo.x; v.y = lo.y; v.z = hi.x; v.w = hi.y;
            *(uint4*)(h + (size_t)node * 1024 + rp * 256 + c16 * 8) = v;
        }
    }
}

__global__ __launch_bounds__(THREADS) void gemm3_kernel(
    half_t* __restrict__ h, const half_t* __restrict__ WfT) {
    __shared__ half_t Ws[128 * 128];               // 32 KB
    const int bid = blockIdx.x;
    const int t = threadIdx.x;
    const int rp = bid & 3;                        // 0..3
    const int mt = bid >> 2;                       // 0..390
    const int m0 = mt * 128;
    const int wave = t >> 6, lane = t & 63;
    if (m0 + 128 <= N_NODES)
        gemm3_body<false>(h, WfT, Ws, m0, rp, wave, lane, t);
    else
        gemm3_body<true>(h, WfT, Ws, m0, rp, wave, lane, t);
}

// ---- reduce: out[d][c] = sum_p h[d][p*256+c]; 4 pair-partials
__global__ __launch_bounds__(THREADS) void reduce_kernel(
    const half_t* __restrict__ h, float* __restrict__ out) {
    int g = blockIdx.x * 4 + (threadIdx.x >> 6);   // 12500 blocks -> g < 50000
    int lane = threadIdx.x & 63;
    const half_t* hb = h + (size_t)g * 1024 + lane * 2;
    half2v v0 = *(const half2v*)(hb + 0 * 256);
    half2v v1 = *(const half2v*)(hb + 1 * 256);
    half2v v2 = *(const half2v*)(hb + 2 * 256);
    half2v v3 = *(const half2v*)(hb + 3 * 256);
    float sx = (float)v0[0] + (float)v1[0] + (float)v2[0] + (float)v3[0];
    float sy = (float)v0[1] + (float)v1[1] + (float)v2[1] + (float)v3[1];
    float2 o; o.x = sx; o.y = sy;
    *(float2*)(out + (size_t)g * 128 + lane * 2) = o;
}

// ---- fallback (tiny ws): wave-per-edge direct with atomics
__global__ void naive_kernel(const float* __restrict__ feat, const float* __restrict__ rel_emb,
                             const float* __restrict__ ew, const int* __restrict__ src,
                             const int* __restrict__ dst, const int* __restrict__ rel,
                             float* __restrict__ out) {
    int wave = (blockIdx.x * blockDim.x + threadIdx.x) >> 6;
    int lane = threadIdx.x & 63;
    if (wave >= N_EDGES) return;
    const float* f = feat + (size_t)src[wave] * IN_DIM;
    const float* W = rel_emb + (size_t)rel[wave] * IN_DIM * OUT_DIM;
    float w = ew[wave];
    float a0 = 0.f, a1 = 0.f;
    for (int k = 0; k < IN_DIM; k++) {
        float fv = f[k];
        a0 += fv * W[k * OUT_DIM + lane];
        a1 += fv * W[k * OUT_DIM + 64 + lane];
    }
    int d = dst[wave];
    atomicAdd(&out[(size_t)d * OUT_DIM + lane], a0 * w);
    atomicAdd(&out[(size_t)d * OUT_DIM + 64 + lane], a1 * w);
}

extern "C" void kernel_launch(void* const* d_in, const int* in_sizes, int n_in,
                              void* d_out, int out_size, void* d_ws, size_t ws_size,
                              hipStream_t stream) {
    const float* feat    = (const float*)d_in[0];
    const float* rel_emb = (const float*)d_in[1];
    const float* ew      = (const float*)d_in[2];
    const int*   src     = (const int*)d_in[3];
    const int*   dst     = (const int*)d_in[4];
    const int*   rel     = (const int*)d_in[5];
    float* out = (float*)d_out;

    if (ws_size >= WS_NEED) {
        char* ws = (char*)d_ws;
        half_t* h    = (half_t*)(ws + WS_H);
        half_t* WfT  = (half_t*)(ws + WS_WFT);
        uint2*  rec  = (uint2*)(ws + WS_REC);
        int*    off  = (int*)(ws + WS_OFF);
        int*    bsum = (int*)(ws + WS_BSUM);
        // d_out scratch (dead until reduce writes out)
        int*    rank  = (int*)((char*)d_out + DO_RANK);
        half_t* featH = (half_t*)((char*)d_out + DO_FEATH);
        int*    hist8 = (int*)((char*)d_out + DO_HIST8);
        int*    off8  = (int*)((char*)d_out + DO_OFF8);

        hipMemsetAsync(hist8, 0, (size_t)8 * NBINS3 * 4, stream);
        prep_kernel<<<PREP_BLOCKS, THREADS, 0, stream>>>(rel_emb, WfT, feat, featH,
                                                         dst, hist8, rank);
        scan1_kernel<<<NB3, 256, 0, stream>>>(hist8, bsum);
        scan2_kernel<<<1, 64, 0, stream>>>(bsum, off);
        scan3_kernel<<<NB3, 256, 0, stream>>>(hist8, bsum, off, off8);
        scatter_kernel<<<RANK_BLOCKS, THREADS, 0, stream>>>(dst, src, rel, ew,
                                                            rank, off8, rec);
        agg_kernel<<<N_NODES / 4, THREADS, 0, stream>>>(featH, rec, off, h);
        gemm3_kernel<<<G3_BLOCKS, THREADS, 0, stream>>>(h, WfT);   // in-place pair partials
        reduce_kernel<<<N_NODES / 4, THREADS, 0, stream>>>(h, out);
    } else {
        hipMemsetAsync(d_out, 0, (size_t)out_size * sizeof(float), stream);
        const long long total = (long long)N_EDGES * 64;
        const int blocks = (int)((total + THREADS - 1) / THREADS);
        naive_kernel<<<blocks, THREADS, 0, stream>>>(feat, rel_emb, ew, src, dst, rel, out);
    }
}